// Round 15
// baseline (73.429 us; speedup 1.0000x reference)
//
#include <hip/hip_runtime.h>
#include <hip/hip_bf16.h>

#define EPSV 1e-8f
#define WSTRIDE 516   // floats; %4==0 (b128-aligned columns), %32==4 (bank spread)

typedef float f32x4 __attribute__((ext_vector_type(4)));

__device__ __forceinline__ float rdlane(float v, int l) {
    return __int_as_float(__builtin_amdgcn_readlane(__float_as_int(v), l));
}

__device__ __forceinline__ void load_w_row(const float* __restrict__ lip_w,
                                           const float* __restrict__ pose_w,
                                           int row, float* w) {
    const float4* lp4 = reinterpret_cast<const float4*>(lip_w + row * 20);
    float4 t0 = lp4[0], t1 = lp4[1], t2 = lp4[2], t3 = lp4[3], t4 = lp4[4];
    const float2* pp2 = reinterpret_cast<const float2*>(pose_w + row * 6);
    float2 u0 = pp2[0], u1 = pp2[1], u2 = pp2[2];
    w[0]  = t0.x + EPSV; w[1]  = t0.y + EPSV; w[2]  = t0.z + EPSV; w[3]  = t0.w + EPSV;
    w[4]  = t1.x + EPSV; w[5]  = t1.y + EPSV; w[6]  = t1.z + EPSV; w[7]  = t1.w + EPSV;
    w[8]  = t2.x + EPSV; w[9]  = t2.y + EPSV; w[10] = t2.z + EPSV; w[11] = t2.w + EPSV;
    w[12] = t3.x + EPSV; w[13] = t3.y + EPSV; w[14] = t3.z + EPSV; w[15] = t3.w + EPSV;
    w[16] = t4.x + EPSV; w[17] = t4.y + EPSV; w[18] = t4.z + EPSV; w[19] = t4.w + EPSV;
    w[20] = u0.x + EPSV; w[21] = u0.y + EPSV;
    w[22] = u1.x + EPSV; w[23] = u1.y + EPSV;
    w[24] = u2.x + EPSV; w[25] = u2.y + EPSV;
}

// ---------------------------------------------------------------------------
// Collapsed Householder step J, Cholesky-assisted (see round-12 notes).
// ---------------------------------------------------------------------------
template<int J>
struct QRStep {
    static __device__ __forceinline__ void run(float (&P)[26], float (&Gt)[26],
                                               float (&R)[26], const int tid) {
        // --- Cholesky step J ---
        const float dJ2  = rdlane(Gt[J], J);              // trailing diag
        const float invd = __builtin_amdgcn_rsqf(dJ2);
        const float dJ   = dJ2 * invd;                    // = sqrt(dJ2)
        const float rcj  = (tid >= J) ? Gt[J] * invd : 0.f;   // Rc[J,c]
#pragma unroll
        for (int i = 0; i < 26; ++i)
            if (i > J) Gt[i] = fmaf(-rdlane(rcj, i), rcj, Gt[i]);

        // --- Householder sign recursion (P = pivot block) ---
        const float alpha = rdlane(P[J], J);
        const float beta  = (alpha >= 0.f) ? -dJ : dJ;    // LAPACK slarfg
        const float bma   = beta - alpha;
        const float tau   = bma * __builtin_amdgcn_rcpf(beta);
        const float rdn   = -__builtin_amdgcn_rcpf(bma);  // 1/(alpha-beta)
        const float S     = fmaf(dJ, rcj, -(alpha * P[J]));
        const float dc    = fmaf(S, rdn, P[J]);
        R[J] = (tid == J) ? beta : fmaf(-tau, dc, P[J]);  // R row J
        const float trd = tau * rdn;
#pragma unroll
        for (int i = 0; i < 26; ++i)
            if (i > J) P[i] = fmaf(-(trd * rdlane(P[i], J)), dc, P[i]);
    }
};

template<int J> struct QRSteps {
    static __device__ __forceinline__ void run(float (&P)[26], float (&Gt)[26],
                                               float (&R)[26], int tid) {
        QRStep<J>::run(P, Gt, R, tid);
        QRSteps<J + 1>::run(P, Gt, R, tid);
    }
};
template<> struct QRSteps<26> {
    static __device__ __forceinline__ void run(float (&)[26], float (&)[26],
                                               float (&)[26], int) {}
};

__global__ __launch_bounds__(512) void qr_kernel(const float* __restrict__ pose_w,
                                                 const float* __restrict__ lip_w,
                                                 float* __restrict__ qt) {
    __shared__ float Wc[26 * WSTRIDE];    // W+EPS, column-major
    __shared__ float Gp[8][26][27];       // per-wave partial Gram
    __shared__ float G[26 * 27 + 8];      // Gram (both triangles)
    __shared__ float Rlds[26][27];
    __shared__ float Rinv[26][27];

    const int tid  = threadIdx.x;
    const int lane = tid & 63;
    const int wid  = tid >> 6;

    // ---- Stage 1: load row tid (KEPT LIVE for stage 4), scatter to LDS ---
    float w[26];
    load_w_row(lip_w, pose_w, tid, w);
#pragma unroll
    for (int c = 0; c < 26; ++c) Wc[c * WSTRIDE + tid] = w[c];
    __syncthreads();

    // ---- Stage 2: Gram G = W^T W, 8-wave parallel over row chunks --------
    if (lane < 45) {
        int tm = 0, rem = lane;
        while (rem >= 9 - tm) { rem -= 9 - tm; ++tm; }
        const int tn = tm + rem;
        const int ra = (tm * 3 > 23) ? 23 : tm * 3;   // clamped tiles overlap but
        const int ca = (tn * 3 > 23) ? 23 : tn * 3;   // write identical values
        const f32x4* A0 = reinterpret_cast<const f32x4*>(&Wc[(ra + 0) * WSTRIDE]);
        const f32x4* A1 = reinterpret_cast<const f32x4*>(&Wc[(ra + 1) * WSTRIDE]);
        const f32x4* A2 = reinterpret_cast<const f32x4*>(&Wc[(ra + 2) * WSTRIDE]);
        const f32x4* B0 = reinterpret_cast<const f32x4*>(&Wc[(ca + 0) * WSTRIDE]);
        const f32x4* B1 = reinterpret_cast<const f32x4*>(&Wc[(ca + 1) * WSTRIDE]);
        const f32x4* B2 = reinterpret_cast<const f32x4*>(&Wc[(ca + 2) * WSTRIDE]);
        float acc[3][3] = {{0.f, 0.f, 0.f}, {0.f, 0.f, 0.f}, {0.f, 0.f, 0.f}};
        const int i0 = 16 * wid;
#pragma unroll 4
        for (int ii = 0; ii < 16; ++ii) {
            const int i = i0 + ii;
            const f32x4 av[3] = {A0[i], A1[i], A2[i]};
            const f32x4 bv[3] = {B0[i], B1[i], B2[i]};
#pragma unroll
            for (int r = 0; r < 3; ++r) {
#pragma unroll
                for (int c = 0; c < 3; ++c) {
                    acc[r][c] = fmaf(av[r].x, bv[c].x, acc[r][c]);
                    acc[r][c] = fmaf(av[r].y, bv[c].y, acc[r][c]);
                    acc[r][c] = fmaf(av[r].z, bv[c].z, acc[r][c]);
                    acc[r][c] = fmaf(av[r].w, bv[c].w, acc[r][c]);
                }
            }
        }
#pragma unroll
        for (int r = 0; r < 3; ++r) {
#pragma unroll
            for (int c = 0; c < 3; ++c) {
                Gp[wid][ra + r][ca + c] = acc[r][c];
                Gp[wid][ca + c][ra + r] = acc[r][c];
            }
        }
    }
    __syncthreads();

    // Reduce the 8 partials: thread t < 351 owns upper-tri pair (r,c).
    if (tid < 351) {
        int r = 0, t = tid;
        while (t >= 26 - r) { t -= 26 - r; ++r; }
        const int c = r + t;
        float s = 0.f;
#pragma unroll
        for (int w8 = 0; w8 < 8; ++w8) s += Gp[w8][r][c];
        G[r * 27 + c] = s;
        G[c * 27 + r] = s;
    }
    __syncthreads();

    // ---- Stage 3: chol-assisted 26-step Householder + back-sub (wave 0) --
    if (tid < 64) {
        const int cc = (tid < 26) ? tid : 25;   // clamp for safe addressing
        float P[26], Gt[26], R[26];
        {   // pivot column cc, rows 0..25, via 7 b128 reads
            const f32x4* pc = reinterpret_cast<const f32x4*>(&Wc[cc * WSTRIDE]);
            const f32x4 q0 = pc[0], q1 = pc[1], q2 = pc[2], q3 = pc[3],
                        q4 = pc[4], q5 = pc[5], q6 = pc[6];
            P[0]=q0.x;  P[1]=q0.y;  P[2]=q0.z;  P[3]=q0.w;
            P[4]=q1.x;  P[5]=q1.y;  P[6]=q1.z;  P[7]=q1.w;
            P[8]=q2.x;  P[9]=q2.y;  P[10]=q2.z; P[11]=q2.w;
            P[12]=q3.x; P[13]=q3.y; P[14]=q3.z; P[15]=q3.w;
            P[16]=q4.x; P[17]=q4.y; P[18]=q4.z; P[19]=q4.w;
            P[20]=q5.x; P[21]=q5.y; P[22]=q5.z; P[23]=q5.w;
            P[24]=q6.x; P[25]=q6.y;
        }
#pragma unroll
        for (int j = 0; j < 26; ++j) Gt[j] = G[j * 27 + cc];

        QRSteps<0>::run(P, Gt, R, tid);

        // Stage R (lane c holds column c); same-wave write->read is ordered.
        if (tid < 26) {
#pragma unroll
            for (int i = 0; i < 26; ++i)
                if (i <= tid) Rlds[i][tid] = R[i];
        }

        // Back-substitution: thread cc solves column cc of R^{-1} (rcp div).
        if (tid < 26) {
            float ri[26];
#pragma unroll
            for (int k = 25; k >= 0; --k) {
                float s = (k == tid) ? 1.f : 0.f;
#pragma unroll
                for (int m = 25; m > k; --m)
                    if (m <= tid) s = fmaf(-Rlds[k][m], ri[m], s);
                ri[k] = s * __builtin_amdgcn_rcpf(Rlds[k][k]);
            }
#pragma unroll
            for (int k = 0; k < 26; ++k)
                if (k <= tid) Rinv[k][tid] = ri[k];
        }
    }
    __syncthreads();

    // ---- Stage 4: Q = W * Rinv using the LIVE w registers (no reload) ----
#pragma unroll
    for (int k = 0; k < 26; ++k) {
        float q = 0.f;
#pragma unroll
        for (int m = 0; m < 26; ++m)
            if (m <= k) q = fmaf(w[m], Rinv[m][k], q);
        qt[k * 512 + tid] = q;
    }
}

// ---------------------------------------------------------------------------
// out[B][512] = input[B][26] @ qt^T   (qt is [26][512])
// Round-14 inner structure (padded LDS rows, 7x b128 row reads, rh-split,
// 16B NT stores) with ONE change: 64-row tiles -> 2048 blocks instead of
// 4096. Halves per-block qf-load bursts and block startup/drain instances;
// per-thread row sweep 16 -> 32 (registers/inner loop unchanged).
// ---------------------------------------------------------------------------

__global__ __launch_bounds__(256) void out_gemm(const float* __restrict__ in,
                                                const float* __restrict__ qt,
                                                float* __restrict__ out) {
    __shared__ __align__(16) float xs[64 * 28];
    const int tid = threadIdx.x;
    const long base = (long)blockIdx.x * 64;

    // Stage 64x26 tile = 1664 floats = 416 f32x4; threads 0..255 load one,
    // threads 0..159 load a second. Scatter into padded rows (magic-mul div).
    {
        const float4* ip4 = reinterpret_cast<const float4*>(in + base * 26);
        float4 v0 = ip4[tid];
        float4 v1 = make_float4(0.f, 0.f, 0.f, 0.f);
        if (tid < 160) v1 = ip4[256 + tid];

        {
            const float vals[4] = {v0.x, v0.y, v0.z, v0.w};
            const int e0 = tid * 4;
#pragma unroll
            for (int q = 0; q < 4; ++q) {
                const int e = e0 + q;
                const int r = e / 26;
                const int c = e - r * 26;
                xs[r * 28 + c] = vals[q];
            }
        }
        if (tid < 160) {
            const float vals[4] = {v1.x, v1.y, v1.z, v1.w};
            const int e0 = (256 + tid) * 4;
#pragma unroll
            for (int q = 0; q < 4; ++q) {
                const int e = e0 + q;
                const int r = e / 26;
                const int c = e - r * 26;
                xs[r * 28 + c] = vals[q];
            }
        }
    }

    const int cg = tid & 127;             // column group: cols 4*cg .. 4*cg+3
    const int rh = tid >> 7;              // row half: rows rh*32 .. rh*32+31

    f32x4 qf[26];
#pragma unroll
    for (int k = 0; k < 26; ++k)
        qf[k] = *reinterpret_cast<const f32x4*>(qt + k * 512 + cg * 4);
    __syncthreads();

    float* op = out + (base + (long)rh * 32) * 512 + cg * 4;
#pragma unroll
    for (int r = 0; r < 32; ++r) {
        const float* xr = xs + (rh * 32 + r) * 28;
        const f32x4 t0 = *reinterpret_cast<const f32x4*>(xr + 0);
        const f32x4 t1 = *reinterpret_cast<const f32x4*>(xr + 4);
        const f32x4 t2 = *reinterpret_cast<const f32x4*>(xr + 8);
        const f32x4 t3 = *reinterpret_cast<const f32x4*>(xr + 12);
        const f32x4 t4 = *reinterpret_cast<const f32x4*>(xr + 16);
        const f32x4 t5 = *reinterpret_cast<const f32x4*>(xr + 20);
        const f32x4 t6 = *reinterpret_cast<const f32x4*>(xr + 24);  // .z/.w unused
        float xv[26];
        xv[0]=t0.x;  xv[1]=t0.y;  xv[2]=t0.z;  xv[3]=t0.w;
        xv[4]=t1.x;  xv[5]=t1.y;  xv[6]=t1.z;  xv[7]=t1.w;
        xv[8]=t2.x;  xv[9]=t2.y;  xv[10]=t2.z; xv[11]=t2.w;
        xv[12]=t3.x; xv[13]=t3.y; xv[14]=t3.z; xv[15]=t3.w;
        xv[16]=t4.x; xv[17]=t4.y; xv[18]=t4.z; xv[19]=t4.w;
        xv[20]=t5.x; xv[21]=t5.y; xv[22]=t5.z; xv[23]=t5.w;
        xv[24]=t6.x; xv[25]=t6.y;
        f32x4 acc = {0.f, 0.f, 0.f, 0.f};
#pragma unroll
        for (int k = 0; k < 26; ++k) {
            acc.x = fmaf(xv[k], qf[k].x, acc.x);
            acc.y = fmaf(xv[k], qf[k].y, acc.y);
            acc.z = fmaf(xv[k], qf[k].z, acc.z);
            acc.w = fmaf(xv[k], qf[k].w, acc.w);
        }
        __builtin_nontemporal_store(acc,
            reinterpret_cast<f32x4*>(op + (long)r * 512));
    }
}

// ---------------------------------------------------------------------------

extern "C" void kernel_launch(void* const* d_in, const int* in_sizes, int n_in,
                              void* d_out, int out_size, void* d_ws, size_t ws_size,
                              hipStream_t stream) {
    const float* input  = (const float*)d_in[0];   // (B, 26)
    const float* pose_w = (const float*)d_in[1];   // (512, 6)
    const float* lip_w  = (const float*)d_in[2];   // (512, 20)
    float* out = (float*)d_out;                    // (B, 512)
    float* qt  = (float*)d_ws;                     // Q^T as [26][512] f32

    const int B = in_sizes[0] / 26;                // 131072 = 64 * 2048

    qr_kernel<<<1, 512, 0, stream>>>(pose_w, lip_w, qt);
    out_gemm<<<(B + 63) / 64, 256, 0, stream>>>(input, qt, out);
}

// Round 16
// 69.926 us; speedup vs baseline: 1.0501x; 1.0501x over previous
//
#include <hip/hip_runtime.h>
#include <hip/hip_bf16.h>

#define EPSV 1e-8f
#define WSTRIDE 516   // floats; %4==0 (b128-aligned columns), %32==4 (bank spread)

typedef float f32x4 __attribute__((ext_vector_type(4)));

__device__ __forceinline__ float rdlane(float v, int l) {
    return __int_as_float(__builtin_amdgcn_readlane(__float_as_int(v), l));
}

__device__ __forceinline__ void load_w_row(const float* __restrict__ lip_w,
                                           const float* __restrict__ pose_w,
                                           int row, float* w) {
    const float4* lp4 = reinterpret_cast<const float4*>(lip_w + row * 20);
    float4 t0 = lp4[0], t1 = lp4[1], t2 = lp4[2], t3 = lp4[3], t4 = lp4[4];
    const float2* pp2 = reinterpret_cast<const float2*>(pose_w + row * 6);
    float2 u0 = pp2[0], u1 = pp2[1], u2 = pp2[2];
    w[0]  = t0.x + EPSV; w[1]  = t0.y + EPSV; w[2]  = t0.z + EPSV; w[3]  = t0.w + EPSV;
    w[4]  = t1.x + EPSV; w[5]  = t1.y + EPSV; w[6]  = t1.z + EPSV; w[7]  = t1.w + EPSV;
    w[8]  = t2.x + EPSV; w[9]  = t2.y + EPSV; w[10] = t2.z + EPSV; w[11] = t2.w + EPSV;
    w[12] = t3.x + EPSV; w[13] = t3.y + EPSV; w[14] = t3.z + EPSV; w[15] = t3.w + EPSV;
    w[16] = t4.x + EPSV; w[17] = t4.y + EPSV; w[18] = t4.z + EPSV; w[19] = t4.w + EPSV;
    w[20] = u0.x + EPSV; w[21] = u0.y + EPSV;
    w[22] = u1.x + EPSV; w[23] = u1.y + EPSV;
    w[24] = u2.x + EPSV; w[25] = u2.y + EPSV;
}

// ---------------------------------------------------------------------------
// Collapsed Householder step J, Cholesky-assisted (see round-12 notes).
// ---------------------------------------------------------------------------
template<int J>
struct QRStep {
    static __device__ __forceinline__ void run(float (&P)[26], float (&Gt)[26],
                                               float (&R)[26], const int tid) {
        // --- Cholesky step J ---
        const float dJ2  = rdlane(Gt[J], J);              // trailing diag
        const float invd = __builtin_amdgcn_rsqf(dJ2);
        const float dJ   = dJ2 * invd;                    // = sqrt(dJ2)
        const float rcj  = (tid >= J) ? Gt[J] * invd : 0.f;   // Rc[J,c]
#pragma unroll
        for (int i = 0; i < 26; ++i)
            if (i > J) Gt[i] = fmaf(-rdlane(rcj, i), rcj, Gt[i]);

        // --- Householder sign recursion (P = pivot block) ---
        const float alpha = rdlane(P[J], J);
        const float beta  = (alpha >= 0.f) ? -dJ : dJ;    // LAPACK slarfg
        const float bma   = beta - alpha;
        const float tau   = bma * __builtin_amdgcn_rcpf(beta);
        const float rdn   = -__builtin_amdgcn_rcpf(bma);  // 1/(alpha-beta)
        const float S     = fmaf(dJ, rcj, -(alpha * P[J]));
        const float dc    = fmaf(S, rdn, P[J]);
        R[J] = (tid == J) ? beta : fmaf(-tau, dc, P[J]);  // R row J
        const float trd = tau * rdn;
#pragma unroll
        for (int i = 0; i < 26; ++i)
            if (i > J) P[i] = fmaf(-(trd * rdlane(P[i], J)), dc, P[i]);
    }
};

template<int J> struct QRSteps {
    static __device__ __forceinline__ void run(float (&P)[26], float (&Gt)[26],
                                               float (&R)[26], int tid) {
        QRStep<J>::run(P, Gt, R, tid);
        QRSteps<J + 1>::run(P, Gt, R, tid);
    }
};
template<> struct QRSteps<26> {
    static __device__ __forceinline__ void run(float (&)[26], float (&)[26],
                                               float (&)[26], int) {}
};

__global__ __launch_bounds__(512) void qr_kernel(const float* __restrict__ pose_w,
                                                 const float* __restrict__ lip_w,
                                                 float* __restrict__ qt) {
    __shared__ float Wc[26 * WSTRIDE];    // W+EPS, column-major
    __shared__ float Gp[8][26][27];       // per-wave partial Gram
    __shared__ float G[26 * 27 + 8];      // Gram (both triangles)
    __shared__ float Rlds[26][27];
    __shared__ float Rinv[26][27];

    const int tid  = threadIdx.x;
    const int lane = tid & 63;
    const int wid  = tid >> 6;

    // ---- Stage 1: load row tid (KEPT LIVE for stage 4), scatter to LDS ---
    float w[26];
    load_w_row(lip_w, pose_w, tid, w);
#pragma unroll
    for (int c = 0; c < 26; ++c) Wc[c * WSTRIDE + tid] = w[c];
    __syncthreads();

    // ---- Stage 2: Gram G = W^T W, 8-wave parallel over row chunks --------
    if (lane < 45) {
        int tm = 0, rem = lane;
        while (rem >= 9 - tm) { rem -= 9 - tm; ++tm; }
        const int tn = tm + rem;
        const int ra = (tm * 3 > 23) ? 23 : tm * 3;   // clamped tiles overlap but
        const int ca = (tn * 3 > 23) ? 23 : tn * 3;   // write identical values
        const f32x4* A0 = reinterpret_cast<const f32x4*>(&Wc[(ra + 0) * WSTRIDE]);
        const f32x4* A1 = reinterpret_cast<const f32x4*>(&Wc[(ra + 1) * WSTRIDE]);
        const f32x4* A2 = reinterpret_cast<const f32x4*>(&Wc[(ra + 2) * WSTRIDE]);
        const f32x4* B0 = reinterpret_cast<const f32x4*>(&Wc[(ca + 0) * WSTRIDE]);
        const f32x4* B1 = reinterpret_cast<const f32x4*>(&Wc[(ca + 1) * WSTRIDE]);
        const f32x4* B2 = reinterpret_cast<const f32x4*>(&Wc[(ca + 2) * WSTRIDE]);
        float acc[3][3] = {{0.f, 0.f, 0.f}, {0.f, 0.f, 0.f}, {0.f, 0.f, 0.f}};
        const int i0 = 16 * wid;
#pragma unroll 4
        for (int ii = 0; ii < 16; ++ii) {
            const int i = i0 + ii;
            const f32x4 av[3] = {A0[i], A1[i], A2[i]};
            const f32x4 bv[3] = {B0[i], B1[i], B2[i]};
#pragma unroll
            for (int r = 0; r < 3; ++r) {
#pragma unroll
                for (int c = 0; c < 3; ++c) {
                    acc[r][c] = fmaf(av[r].x, bv[c].x, acc[r][c]);
                    acc[r][c] = fmaf(av[r].y, bv[c].y, acc[r][c]);
                    acc[r][c] = fmaf(av[r].z, bv[c].z, acc[r][c]);
                    acc[r][c] = fmaf(av[r].w, bv[c].w, acc[r][c]);
                }
            }
        }
#pragma unroll
        for (int r = 0; r < 3; ++r) {
#pragma unroll
            for (int c = 0; c < 3; ++c) {
                Gp[wid][ra + r][ca + c] = acc[r][c];
                Gp[wid][ca + c][ra + r] = acc[r][c];
            }
        }
    }
    __syncthreads();

    // Reduce the 8 partials: thread t < 351 owns upper-tri pair (r,c).
    if (tid < 351) {
        int r = 0, t = tid;
        while (t >= 26 - r) { t -= 26 - r; ++r; }
        const int c = r + t;
        float s = 0.f;
#pragma unroll
        for (int w8 = 0; w8 < 8; ++w8) s += Gp[w8][r][c];
        G[r * 27 + c] = s;
        G[c * 27 + r] = s;
    }
    __syncthreads();

    // ---- Stage 3: chol-assisted 26-step Householder + back-sub (wave 0) --
    if (tid < 64) {
        const int cc = (tid < 26) ? tid : 25;   // clamp for safe addressing
        float P[26], Gt[26], R[26];
        {   // pivot column cc, rows 0..25, via 7 b128 reads
            const f32x4* pc = reinterpret_cast<const f32x4*>(&Wc[cc * WSTRIDE]);
            const f32x4 q0 = pc[0], q1 = pc[1], q2 = pc[2], q3 = pc[3],
                        q4 = pc[4], q5 = pc[5], q6 = pc[6];
            P[0]=q0.x;  P[1]=q0.y;  P[2]=q0.z;  P[3]=q0.w;
            P[4]=q1.x;  P[5]=q1.y;  P[6]=q1.z;  P[7]=q1.w;
            P[8]=q2.x;  P[9]=q2.y;  P[10]=q2.z; P[11]=q2.w;
            P[12]=q3.x; P[13]=q3.y; P[14]=q3.z; P[15]=q3.w;
            P[16]=q4.x; P[17]=q4.y; P[18]=q4.z; P[19]=q4.w;
            P[20]=q5.x; P[21]=q5.y; P[22]=q5.z; P[23]=q5.w;
            P[24]=q6.x; P[25]=q6.y;
        }
#pragma unroll
        for (int j = 0; j < 26; ++j) Gt[j] = G[j * 27 + cc];

        QRSteps<0>::run(P, Gt, R, tid);

        // Stage R (lane c holds column c); same-wave write->read is ordered.
        if (tid < 26) {
#pragma unroll
            for (int i = 0; i < 26; ++i)
                if (i <= tid) Rlds[i][tid] = R[i];
        }

        // Back-substitution: thread cc solves column cc of R^{-1} (rcp div).
        if (tid < 26) {
            float ri[26];
#pragma unroll
            for (int k = 25; k >= 0; --k) {
                float s = (k == tid) ? 1.f : 0.f;
#pragma unroll
                for (int m = 25; m > k; --m)
                    if (m <= tid) s = fmaf(-Rlds[k][m], ri[m], s);
                ri[k] = s * __builtin_amdgcn_rcpf(Rlds[k][k]);
            }
#pragma unroll
            for (int k = 0; k < 26; ++k)
                if (k <= tid) Rinv[k][tid] = ri[k];
        }
    }
    __syncthreads();

    // ---- Stage 4: Q = W * Rinv using the LIVE w registers (no reload) ----
    // All 512 threads, 1 row each; Rinv reads are LDS broadcasts; stores
    // coalesced (qt[k*512 + tid], 2 KB per k across the block).
#pragma unroll
    for (int k = 0; k < 26; ++k) {
        float q = 0.f;
#pragma unroll
        for (int m = 0; m < 26; ++m)
            if (m <= k) q = fmaf(w[m], Rinv[m][k], q);
        qt[k * 512 + tid] = q;
    }
}

// ---------------------------------------------------------------------------
// out[B][512] = input[B][26] @ qt^T   (qt is [26][512])
// Best measured structure (round 14, 69.97 us): 4096 independent blocks,
// 32-row padded LDS tile, 7x b128 row reads, rh-split, NT f32x4 stores.
// Bracketing probes confirmed this is a local optimum: NT>plain (+14.5),
// 32-row > 64-row (+3.5) > grid-stride (+3), f32x4 > f32x2 stores (+4),
// LDS-staged x > scalar/SMEM x (+6), packed FMA = scalar FMA (null).
// ---------------------------------------------------------------------------

__global__ __launch_bounds__(256) void out_gemm(const float* __restrict__ in,
                                                const float* __restrict__ qt,
                                                float* __restrict__ out) {
    __shared__ __align__(16) float xs[32 * 28];
    const int tid = threadIdx.x;
    const long base = (long)blockIdx.x * 32;

    if (tid < 208) {
        const float4 v = reinterpret_cast<const float4*>(in + base * 26)[tid];
        const float vals[4] = {v.x, v.y, v.z, v.w};
        const int e0 = tid * 4;
#pragma unroll
        for (int q = 0; q < 4; ++q) {
            const int e = e0 + q;
            const int r = e / 26;
            const int c = e - r * 26;
            xs[r * 28 + c] = vals[q];
        }
    }

    const int cg = tid & 127;             // column group: cols 4*cg .. 4*cg+3
    const int rh = tid >> 7;              // row half: 0 or 1

    f32x4 qf[26];
#pragma unroll
    for (int k = 0; k < 26; ++k)
        qf[k] = *reinterpret_cast<const f32x4*>(qt + k * 512 + cg * 4);
    __syncthreads();

    float* op = out + (base + (long)rh * 16) * 512 + cg * 4;
#pragma unroll
    for (int r = 0; r < 16; ++r) {
        const float* xr = xs + (rh * 16 + r) * 28;
        const f32x4 t0 = *reinterpret_cast<const f32x4*>(xr + 0);
        const f32x4 t1 = *reinterpret_cast<const f32x4*>(xr + 4);
        const f32x4 t2 = *reinterpret_cast<const f32x4*>(xr + 8);
        const f32x4 t3 = *reinterpret_cast<const f32x4*>(xr + 12);
        const f32x4 t4 = *reinterpret_cast<const f32x4*>(xr + 16);
        const f32x4 t5 = *reinterpret_cast<const f32x4*>(xr + 20);
        const f32x4 t6 = *reinterpret_cast<const f32x4*>(xr + 24);  // .z/.w unused
        float xv[26];
        xv[0]=t0.x;  xv[1]=t0.y;  xv[2]=t0.z;  xv[3]=t0.w;
        xv[4]=t1.x;  xv[5]=t1.y;  xv[6]=t1.z;  xv[7]=t1.w;
        xv[8]=t2.x;  xv[9]=t2.y;  xv[10]=t2.z; xv[11]=t2.w;
        xv[12]=t3.x; xv[13]=t3.y; xv[14]=t3.z; xv[15]=t3.w;
        xv[16]=t4.x; xv[17]=t4.y; xv[18]=t4.z; xv[19]=t4.w;
        xv[20]=t5.x; xv[21]=t5.y; xv[22]=t5.z; xv[23]=t5.w;
        xv[24]=t6.x; xv[25]=t6.y;
        f32x4 acc = {0.f, 0.f, 0.f, 0.f};
#pragma unroll
        for (int k = 0; k < 26; ++k) {
            acc.x = fmaf(xv[k], qf[k].x, acc.x);
            acc.y = fmaf(xv[k], qf[k].y, acc.y);
            acc.z = fmaf(xv[k], qf[k].z, acc.z);
            acc.w = fmaf(xv[k], qf[k].w, acc.w);
        }
        __builtin_nontemporal_store(acc,
            reinterpret_cast<f32x4*>(op + (long)r * 512));
    }
}

// ---------------------------------------------------------------------------

extern "C" void kernel_launch(void* const* d_in, const int* in_sizes, int n_in,
                              void* d_out, int out_size, void* d_ws, size_t ws_size,
                              hipStream_t stream) {
    const float* input  = (const float*)d_in[0];   // (B, 26)
    const float* pose_w = (const float*)d_in[1];   // (512, 6)
    const float* lip_w  = (const float*)d_in[2];   // (512, 20)
    float* out = (float*)d_out;                    // (B, 512)
    float* qt  = (float*)d_ws;                     // Q^T as [26][512] f32

    const int B = in_sizes[0] / 26;

    qr_kernel<<<1, 512, 0, stream>>>(pose_w, lip_w, qt);
    out_gemm<<<(B + 31) / 32, 256, 0, stream>>>(input, qt, out);
}